// Round 3
// baseline (4313.906 us; speedup 1.0000x reference)
//
#include <hip/hip_runtime.h>
#include <hip/hip_bf16.h>

using bf16 = __hip_bfloat16;

typedef __attribute__((ext_vector_type(8))) short short8;   // 8 bf16 (4 VGPRs) MFMA frag
typedef __attribute__((ext_vector_type(4))) float floatx4;  // MFMA accumulator

#define BB 32
#define TT 48
#define SS 128
#define HH 768
#define VV 28996

__device__ __forceinline__ float sigmoidf_(float x) { return 1.0f / (1.0f + expf(-x)); }
__device__ __forceinline__ float tanhf_(float x) {
    float xx = fminf(fmaxf(x, -15.0f), 15.0f);
    float e = expf(2.0f * xx);
    return (e - 1.0f) / (e + 1.0f);
}

// ---------------------------------------------------------------------------
// Coherent (cross-XCD) helpers: agent-scope relaxed atomics compile to
// sc1-flagged global ops that bypass the non-coherent per-XCD L2 and are
// served by the LLC. No cache-wide fences needed anywhere.
// ---------------------------------------------------------------------------
__device__ __forceinline__ float ld1cg(const float* p) {
    return __hip_atomic_load((float*)p, __ATOMIC_RELAXED, __HIP_MEMORY_SCOPE_AGENT);
}
__device__ __forceinline__ float2 ld2cg(const float* p) {
    unsigned long long u = __hip_atomic_load((unsigned long long*)p,
                                             __ATOMIC_RELAXED, __HIP_MEMORY_SCOPE_AGENT);
    union { unsigned long long u; float2 f; } c; c.u = u; return c.f;
}
__device__ __forceinline__ void st1cg(float* p, float v) {
    __hip_atomic_store(p, v, __ATOMIC_RELAXED, __HIP_MEMORY_SCOPE_AGENT);
}

// ---------------------------------------------------------------------------
// Split f32 -> bf16 hi + bf16 lo (lo = rounded residual); combined ~2^-17 rel.
// ---------------------------------------------------------------------------
__device__ __forceinline__ void split1(float v, bf16& h, bf16& l) {
    h = (bf16)v;
    l = (bf16)(v - __bfloat162float(h));
}

// counts (in float4 quads unless noted)
#define XQ    294912   // x:    1536*768/4
#define WIHQ  442368   // Wih:  2304*768/4
#define EQ    786432   // E:    4096*768/4
#define WC1Q  147456   // Wc1:  768*768/4 (compacted from W_ctx[:, :768])
#define WATS  589824   // WatT: 768*768 scalars (transpose)

__global__ __launch_bounds__(256)
void split_ops(const float* __restrict__ x, const float* __restrict__ Wih,
               const float* __restrict__ E, const float* __restrict__ Wctx,
               const float* __restrict__ Watt,
               bf16* __restrict__ xh, bf16* __restrict__ xl,
               bf16* __restrict__ wihh, bf16* __restrict__ wihl,
               bf16* __restrict__ eh, bf16* __restrict__ el,
               bf16* __restrict__ wc1h, bf16* __restrict__ wc1l,
               bf16* __restrict__ wath, bf16* __restrict__ watl)
{
    int idx = blockIdx.x * 256 + threadIdx.x;
    if (idx < XQ + WIHQ + EQ) {
        const float* src; bf16 *dh, *dl; int off;
        if (idx < XQ)            { src = x;   dh = xh;   dl = xl;   off = idx; }
        else if (idx < XQ + WIHQ){ src = Wih; dh = wihh; dl = wihl; off = idx - XQ; }
        else                     { src = E;   dh = eh;   dl = el;   off = idx - XQ - WIHQ; }
        float4 v = ((const float4*)src)[off];
        union { bf16 b[4]; uint2 u; } oh, ol;
        split1(v.x, oh.b[0], ol.b[0]); split1(v.y, oh.b[1], ol.b[1]);
        split1(v.z, oh.b[2], ol.b[2]); split1(v.w, oh.b[3], ol.b[3]);
        ((uint2*)dh)[off] = oh.u; ((uint2*)dl)[off] = ol.u;
    } else if (idx < XQ + WIHQ + EQ + WC1Q) {
        int rem = idx - XQ - WIHQ - EQ;          // j*192 + c4
        int j = rem / 192, c4 = rem - j * 192;
        float4 v = *(const float4*)(Wctx + (size_t)j * 1536 + 4 * c4);
        union { bf16 b[4]; uint2 u; } oh, ol;
        split1(v.x, oh.b[0], ol.b[0]); split1(v.y, oh.b[1], ol.b[1]);
        split1(v.z, oh.b[2], ol.b[2]); split1(v.w, oh.b[3], ol.b[3]);
        ((uint2*)wc1h)[rem] = oh.u; ((uint2*)wc1l)[rem] = ol.u;
    } else if (idx < XQ + WIHQ + EQ + WC1Q + WATS) {
        int rem = idx - XQ - WIHQ - EQ - WC1Q;   // n*768 + k
        int n = rem / 768, k = rem - n * 768;
        float v = Watt[(size_t)k * 768 + n];     // WatT[n][k] = W_att[k][n]
        bf16 h, l; split1(v, h, l);
        wath[rem] = h; watl[rem] = l;
    }
}

// gbias[b*S+s] = b_att . E[b,s,:]; also seeds Sc ping buffer 0 (step-0 init)
__global__ __launch_bounds__(256)
void gbias_k(const float* __restrict__ E, const float* __restrict__ batt,
             float* __restrict__ gbias, float* __restrict__ Sc0)
{
    int row = blockIdx.x * 4 + (threadIdx.x >> 6);
    int lane = threadIdx.x & 63;
    const float* er = E + (size_t)row * 768;
    float acc = 0.f;
#pragma unroll
    for (int i = 0; i < 12; ++i) acc += er[i * 64 + lane] * batt[i * 64 + lane];
#pragma unroll
    for (int d = 32; d > 0; d >>= 1) acc += __shfl_xor(acc, d);
    if (lane == 0) { gbias[row] = acc; st1cg(&Sc0[row], acc); }
}

// W_pred f32 -> bf16 (logits operand; off the recurrent path, bf16 is safe)
#define WPQ 5567232   // 28996*768/4
__global__ __launch_bounds__(256)
void conv_pred(const float* __restrict__ Wp, bf16* __restrict__ Wpb)
{
    int idx = blockIdx.x * 256 + threadIdx.x;
    if (idx >= WPQ) return;
    float4 v = ((const float4*)Wp)[idx];
    union { bf16 b[4]; uint2 u; } o;
    o.b[0] = (bf16)v.x; o.b[1] = (bf16)v.y; o.b[2] = (bf16)v.z; o.b[3] = (bf16)v.w;
    ((uint2*)Wpb)[idx] = o.u;
}

// ---------------------------------------------------------------------------
// Split-bf16 near-f32 GEMM: C[m,n] = sum_k A[m,k]*B[n,k] (+bias[n]), f32 out.
// ---------------------------------------------------------------------------
__global__ __launch_bounds__(256)
void gemm_split(const bf16* __restrict__ Ahi, const bf16* __restrict__ Alo, int lda,
                const bf16* __restrict__ Bhi, const bf16* __restrict__ Blo, int ldb,
                const float* __restrict__ bias,
                float* __restrict__ C, int ldc, int M, int N, int K)
{
    __shared__ __align__(16) char smem[65536];  // Ahi|Alo|Bhi|Blo 16KB each
    const int tid  = threadIdx.x;
    const int lane = tid & 63;
    const int widx = tid >> 6;
    const int wm = widx >> 1, wn = widx & 1;
    const int m0 = blockIdx.y * 128, n0 = blockIdx.x * 128;

    floatx4 acc[4][4];
    const floatx4 fzero = {0.f, 0.f, 0.f, 0.f};
#pragma unroll
    for (int i = 0; i < 4; ++i)
#pragma unroll
        for (int j = 0; j < 4; ++j) acc[i][j] = fzero;

    const int srow = tid >> 3, sslot = tid & 7;

    for (int kb = 0; kb < K; kb += 64) {
        __syncthreads();
        const bf16* mats[4] = {Ahi, Alo, Bhi, Blo};
#pragma unroll
        for (int mt = 0; mt < 4; ++mt) {
            const bf16* base = mats[mt];
            int ld   = (mt < 2) ? lda : ldb;
            int row0 = (mt < 2) ? m0 : n0;
#pragma unroll
            for (int r = 0; r < 4; ++r) {
                int row = r * 32 + srow;
                int c = sslot ^ (row & 7);
                const bf16* gp = base + (size_t)(row0 + row) * ld + kb + c * 8;
                char* lp = smem + mt * 16384 + r * 4096 + widx * 1024;
                __builtin_amdgcn_global_load_lds(
                    (const __attribute__((address_space(1))) void*)gp,
                    (__attribute__((address_space(3))) void*)lp, 16, 0, 0);
            }
        }
        __syncthreads();
#pragma unroll
        for (int kc = 0; kc < 2; ++kc) {
            short8 ah[4], al[4], bh[4], bl[4];
#pragma unroll
            for (int i = 0; i < 4; ++i) {
                int mrow = wm * 64 + i * 16 + (lane & 15);
                int nrow = wn * 64 + i * 16 + (lane & 15);
                int ca = kc * 4 + (lane >> 4);
                int sm = (ca ^ (mrow & 7)) * 16, sn = (ca ^ (nrow & 7)) * 16;
                ah[i] = *(const short8*)(smem +         mrow * 128 + sm);
                al[i] = *(const short8*)(smem + 16384 + mrow * 128 + sm);
                bh[i] = *(const short8*)(smem + 32768 + nrow * 128 + sn);
                bl[i] = *(const short8*)(smem + 49152 + nrow * 128 + sn);
            }
#pragma unroll
            for (int i = 0; i < 4; ++i)
#pragma unroll
                for (int j = 0; j < 4; ++j) {
                    acc[i][j] = __builtin_amdgcn_mfma_f32_16x16x32_bf16(ah[i], bh[j], acc[i][j], 0, 0, 0);
                    acc[i][j] = __builtin_amdgcn_mfma_f32_16x16x32_bf16(ah[i], bl[j], acc[i][j], 0, 0, 0);
                    acc[i][j] = __builtin_amdgcn_mfma_f32_16x16x32_bf16(al[i], bh[j], acc[i][j], 0, 0, 0);
                }
        }
    }
#pragma unroll
    for (int i = 0; i < 4; ++i) {
        int gm0 = m0 + wm * 64 + i * 16 + (lane >> 4) * 4;
#pragma unroll
        for (int j = 0; j < 4; ++j) {
            int gn = n0 + wn * 64 + j * 16 + (lane & 15);
            float bv = bias ? bias[gn] : 0.0f;
#pragma unroll
            for (int r2 = 0; r2 < 4; ++r2)
                C[(size_t)(gm0 + r2) * ldc + gn] = acc[i][j][r2] + bv;
        }
    }
}

// ---------------------------------------------------------------------------
// Plain bf16 MFMA GEMM (m97-style) for the logits: f32 out, N edge handled.
// ---------------------------------------------------------------------------
__global__ __launch_bounds__(256)
void gemm_bt(const bf16* __restrict__ A, int lda,
             const bf16* __restrict__ Bm, int ldb,
             const float* __restrict__ bias,
             float* __restrict__ C, int ldc, int M, int N, int K)
{
    __shared__ __align__(16) char smem[32768];
    const int tid  = threadIdx.x;
    const int lane = tid & 63;
    const int widx = tid >> 6;
    const int wm = widx >> 1, wn = widx & 1;
    const int m0 = blockIdx.y * 128, n0 = blockIdx.x * 128;

    floatx4 acc[4][4];
    const floatx4 fzero = {0.f, 0.f, 0.f, 0.f};
#pragma unroll
    for (int i = 0; i < 4; ++i)
#pragma unroll
        for (int j = 0; j < 4; ++j) acc[i][j] = fzero;

    const int srow = tid >> 3, sslot = tid & 7;

    for (int kb = 0; kb < K; kb += 64) {
        __syncthreads();
#pragma unroll
        for (int r = 0; r < 4; ++r) {
            int mrow = r * 32 + srow;
            int c = sslot ^ (mrow & 7);
            const bf16* gp = A + (size_t)(m0 + mrow) * lda + kb + c * 8;
            char* lp = smem + r * 4096 + widx * 1024;
            __builtin_amdgcn_global_load_lds(
                (const __attribute__((address_space(1))) void*)gp,
                (__attribute__((address_space(3))) void*)lp, 16, 0, 0);
        }
#pragma unroll
        for (int r = 0; r < 4; ++r) {
            int nrow = r * 32 + srow;
            int gn = n0 + nrow; if (gn > N - 1) gn = N - 1;
            int c = sslot ^ (nrow & 7);
            const bf16* gp = Bm + (size_t)gn * ldb + kb + c * 8;
            char* lp = smem + 16384 + r * 4096 + widx * 1024;
            __builtin_amdgcn_global_load_lds(
                (const __attribute__((address_space(1))) void*)gp,
                (__attribute__((address_space(3))) void*)lp, 16, 0, 0);
        }
        __syncthreads();
#pragma unroll
        for (int kc = 0; kc < 2; ++kc) {
            short8 af[4], bfr[4];
#pragma unroll
            for (int i = 0; i < 4; ++i) {
                int mrow = wm * 64 + i * 16 + (lane & 15);
                int nrow = wn * 64 + i * 16 + (lane & 15);
                int ca = kc * 4 + (lane >> 4);
                af[i]  = *(const short8*)(smem +         mrow * 128 + ((ca ^ (mrow & 7)) * 16));
                bfr[i] = *(const short8*)(smem + 16384 + nrow * 128 + ((ca ^ (nrow & 7)) * 16));
            }
#pragma unroll
            for (int i = 0; i < 4; ++i)
#pragma unroll
                for (int j = 0; j < 4; ++j)
                    acc[i][j] = __builtin_amdgcn_mfma_f32_16x16x32_bf16(af[i], bfr[j], acc[i][j], 0, 0, 0);
        }
    }
#pragma unroll
    for (int i = 0; i < 4; ++i) {
        int gm0 = m0 + wm * 64 + i * 16 + (lane >> 4) * 4;
#pragma unroll
        for (int j = 0; j < 4; ++j) {
            int gn = n0 + wn * 64 + j * 16 + (lane & 15);
            if (gn < N) {
                float bv = bias ? bias[gn] : 0.0f;
#pragma unroll
                for (int r2 = 0; r2 < 4; ++r2)
                    C[(size_t)(gm0 + r2) * ldc + gn] = acc[i][j][r2] + bv;
            }
        }
    }
}

// ---------------------------------------------------------------------------
// M [4096][768] -> Mt [768][4096]  (j-major: used for both F->Ft and G->Gt)
// ---------------------------------------------------------------------------
__global__ __launch_bounds__(256)
void transpose_f(const float* __restrict__ F, float* __restrict__ Ft)
{
    __shared__ float tile[32][33];
    int tx = threadIdx.x & 31, ty = threadIdx.x >> 5;  // ty<8
    int r0 = blockIdx.x << 5, j0 = blockIdx.y << 5;
#pragma unroll
    for (int i = 0; i < 4; ++i)
        tile[ty + 8 * i][tx] = F[(size_t)(r0 + ty + 8 * i) * 768 + j0 + tx];
    __syncthreads();
#pragma unroll
    for (int i = 0; i < 4; ++i)
        Ft[(size_t)(j0 + ty + 8 * i) * 4096 + r0 + tx] = tile[tx][ty + 8 * i];
}

// ---------------------------------------------------------------------------
// FENCE-FREE software grid barrier (96 arrivals, 8 spread counter lines).
// __syncthreads() drains vmcnt(0) before s_barrier => every thread's coherent
// stores/atomics are at the LLC before thread 0 arrives. Monotonic counters.
// ---------------------------------------------------------------------------
#define NBLK 96
#define NBARL 8
__device__ __forceinline__ void grid_barrier(unsigned int* bars, unsigned int target)
{
    __syncthreads();                    // drains vmcnt(0): coherent stores done
    if (threadIdx.x == 0) {
        atomicAdd(&bars[(blockIdx.x & (NBARL - 1)) * 32], 1u);
        unsigned int s;
        do {
            __builtin_amdgcn_s_sleep(1);
            s = 0;
#pragma unroll
            for (int i = 0; i < NBARL; ++i)
                s += __hip_atomic_load(&bars[i * 32], __ATOMIC_RELAXED,
                                       __HIP_MEMORY_SCOPE_AGENT);
        } while (s < target);
    }
    __syncthreads();
}

// ---------------------------------------------------------------------------
// All-CU sequential decoder v3. 96 blocks x 512 threads; block owns 8 hidden
// dims (32 weight rows in LDS ~96KB, loaded once). TWO grid barriers/step:
//  phase1: gates matvec (coherent h_prev) -> h_t -> own-dim score partials
//          (atomicAdd into ping-pong Sc, pre-seeded with gbias)      -> bar1
//  phase2: softmax (coherent Sc) + c2 matvec (coherent h_t) + ctx(Ft)
//          -> h_new; seed Sc[next] with gbias                        -> bar2
// All recurrent math f32. Cross-block state only via sc1 LLC ops.
// ---------------------------------------------------------------------------
__global__ __launch_bounds__(512)
void seq_coop(const float* __restrict__ gi,     // [B*T][2304]
              const float* __restrict__ Gt,     // [768][B*S]
              const float* __restrict__ Ft,     // [768][B*S]
              const float* __restrict__ gbias,  // [B*S]
              const float* __restrict__ h0,     // [B][768]
              const float* __restrict__ Whh,    // [2304][768] (raw input)
              const float* __restrict__ Wctx,   // [768][1536] (raw input)
              const float* __restrict__ bhh,    // [2304]
              const float* __restrict__ bctx,   // [768]
              float* __restrict__ Ha,           // [32][768]  h_new (post-attn)
              float* __restrict__ Hb,           // [32][768]  h_t (post-GRU)
              float* __restrict__ Sc,           // [2][32*128] ping-pong scores
              unsigned int* __restrict__ bar,
              bf16* __restrict__ Hseq)          // [B*T][768]
{
    const int bid  = blockIdx.x;
    const int tid  = threadIdx.x;
    const int w    = tid >> 6;          // 8 waves
    const int lane = tid & 63;
    const int kg   = lane & 7;          // k sub-chunk within wave
    const int bo   = lane >> 3;         // batch offset: b = bo + 8q
    const int j0   = bid * 8;

    __shared__ __align__(16) float Wlds[32][768];   // rr = gate*8+jj (r,z,n), 24+jj (c2)
    __shared__ __align__(16) char  scr[24576];      // phase1: part[8][24][32]
                                                    // phase2: pT[128][33] | ctxp[8][2][32]
    __shared__ float partc2[8][8][32];
    __shared__ float redsum[24][32];
    __shared__ float h8[8][32];

    float (*part)[24][32] = (float (*)[24][32])scr;
    float (*pT)[33]       = (float (*)[33])scr;
    float (*ctxp)[2][32]  = (float (*)[2][32])(scr + 16896);

    // ---- load the block's 32 weight rows into LDS (once) ----
    for (int idx = tid; idx < 32 * 768; idx += 512) {
        int rr = idx / 768, k = idx - rr * 768;
        float v;
        if (rr < 24) {
            int gate = rr >> 3, jj = rr & 7;
            v = Whh[(size_t)(gate * 768 + j0 + jj) * 768 + k];
        } else {
            int jj = rr - 24;
            v = Wctx[(size_t)(j0 + jj) * 1536 + 768 + k];
        }
        (&Wlds[0][0])[idx] = v;
    }

    // hoisted pointwise constants (threads 0..255: jj = tid>>5, b = tid&31)
    float bhr = 0.f, bhz = 0.f, bhn = 0.f, bcv = 0.f;
    if (tid < 256) {
        int jj = tid >> 5;
        bhr = bhh[j0 + jj]; bhz = bhh[768 + j0 + jj]; bhn = bhh[1536 + j0 + jj];
        bcv = bctx[j0 + jj];
    }
    const int k4b = 3 * (8 * w + kg);   // this lane's float4 k-chunk (x3)

    unsigned int target = NBLK;
    __syncthreads();

#pragma unroll 1
    for (int t = 0; t < TT; ++t) {
        const float* hp = (t == 0) ? h0 : Ha;
        float* Sc_cur = Sc + (t & 1) * (BB * SS);
        float* Sc_nxt = Sc + ((t + 1) & 1) * (BB * SS);

        // early pointwise-input loads (latency hidden under the k-loop)
        float e_ir = 0.f, e_iz = 0.f, e_inn = 0.f, e_hprev = 0.f;
        if (tid < 256) {
            int jj = tid >> 5, bb = tid & 31;
            const float* gir = gi + (size_t)(bb * TT + t) * 2304 + j0 + jj;
            e_ir = gir[0]; e_iz = gir[768]; e_inn = gir[1536];
            e_hprev = ld1cg(hp + bb * 768 + j0 + jj);
        }

        // ---- Phase 1a: gates matvec, 24 rows (r,z,n) vs h_prev ----
        {
            const float* hp_b = hp + bo * 768 + 4 * k4b;
            float2 h2[4][6];
#pragma unroll
            for (int q = 0; q < 4; ++q) {
                const float* hq = hp_b + q * 8 * 768;
#pragma unroll
                for (int i = 0; i < 6; ++i) h2[q][i] = ld2cg(hq + 2 * i);
            }
#pragma unroll
            for (int half = 0; half < 2; ++half) {
                float acc[12][4];
#pragma unroll
                for (int r = 0; r < 12; ++r)
#pragma unroll
                    for (int q = 0; q < 4; ++q) acc[r][q] = 0.f;
#pragma unroll
                for (int r = 0; r < 12; ++r) {
                    const float* wr_ = &Wlds[half * 12 + r][4 * k4b];
#pragma unroll
                    for (int i = 0; i < 6; ++i) {
                        float2 w2 = *(const float2*)(wr_ + 2 * i);
#pragma unroll
                        for (int q = 0; q < 4; ++q)
                            acc[r][q] += w2.x * h2[q][i].x + w2.y * h2[q][i].y;
                    }
                }
#pragma unroll
                for (int r = 0; r < 12; ++r)
#pragma unroll
                    for (int q = 0; q < 4; ++q) {
                        float v = acc[r][q];
                        v += __shfl_xor(v, 1); v += __shfl_xor(v, 2); v += __shfl_xor(v, 4);
                        if (kg == 0) part[w][half * 12 + r][bo + 8 * q] = v;
                    }
            }
        }
        __syncthreads();
        for (int o = tid; o < 768; o += 512) {
            int rr = o >> 5, bb = o & 31;
            float s = 0.f;
#pragma unroll
            for (int ww = 0; ww < 8; ++ww) s += part[ww][rr][bb];
            redsum[rr][bb] = s;
        }
        __syncthreads();
        if (tid < 256) {
            int jj = tid >> 5, bb = tid & 31;
            float r = sigmoidf_(e_ir + redsum[jj][bb] + bhr);
            float z = sigmoidf_(e_iz + redsum[8 + jj][bb] + bhz);
            float n = tanhf_(e_inn + r * (redsum[16 + jj][bb] + bhn));
            float ht = (1.f - z) * n + z * e_hprev;
            st1cg(&Hb[bb * 768 + j0 + jj], ht);
            Hseq[(size_t)(bb * TT + t) * 768 + j0 + jj] = (bf16)ht;
            h8[jj][bb] = ht;
        }
        __syncthreads();
        // ---- Phase 1b: own-dim score partials -> atomicAdd into Sc_cur ----
        {
            int bb = tid >> 4, so = tid & 15;        // batch, s-octet
            const float* gt0 = Gt + (size_t)j0 * 4096 + bb * 128 + so * 8;
            float p[8];
#pragma unroll
            for (int si = 0; si < 8; ++si) p[si] = 0.f;
#pragma unroll
            for (int jj = 0; jj < 8; ++jj) {
                float hv = h8[jj][bb];
                float4 g0 = *(const float4*)(gt0 + (size_t)jj * 4096);
                float4 g1 = *(const float4*)(gt0 + (size_t)jj * 4096 + 4);
                p[0] += hv * g0.x; p[1] += hv * g0.y; p[2] += hv * g0.z; p[3] += hv * g0.w;
                p[4] += hv * g1.x; p[5] += hv * g1.y; p[6] += hv * g1.z; p[7] += hv * g1.w;
            }
            float* scp = Sc_cur + bb * 128 + so * 8;
#pragma unroll
            for (int si = 0; si < 8; ++si) atomicAdd(scp + si, p[si]);
        }
        grid_barrier(bar, target); target += NBLK;

        // ---- Phase 2: c2 matvec + softmax + ctx + h_new ----
        {
            const float* hb_b = Hb + bo * 768 + 4 * k4b;
            float2 h2[4][6];
#pragma unroll
            for (int q = 0; q < 4; ++q) {
                const float* hq = hb_b + q * 8 * 768;
#pragma unroll
                for (int i = 0; i < 6; ++i) h2[q][i] = ld2cg(hq + 2 * i);
            }
            float a2[8][4];
#pragma unroll
            for (int r = 0; r < 8; ++r)
#pragma unroll
                for (int q = 0; q < 4; ++q) a2[r][q] = 0.f;
#pragma unroll
            for (int r = 0; r < 8; ++r) {
                const float* wr_ = &Wlds[24 + r][4 * k4b];
#pragma unroll
                for (int i = 0; i < 6; ++i) {
                    float2 w2 = *(const float2*)(wr_ + 2 * i);
#pragma unroll
                    for (int q = 0; q < 4; ++q)
                        a2[r][q] += w2.x * h2[q][i].x + w2.y * h2[q][i].y;
                }
            }
#pragma unroll
            for (int r = 0; r < 8; ++r)
#pragma unroll
                for (int q = 0; q < 4; ++q) {
                    float v = a2[r][q];
                    v += __shfl_xor(v, 1); v += __shfl_xor(v, 2); v += __shfl_xor(v, 4);
                    if (kg == 0) partc2[w][r][bo + 8 * q] = v;
                }
        }
        {   // softmax: wave w -> batches 4w..4w+3 (coherent Sc reads)
#pragma unroll
            for (int q = 0; q < 4; ++q) {
                int bb = 4 * w + q;
                float v0 = ld1cg(&Sc_cur[bb * 128 + lane]);
                float v1 = ld1cg(&Sc_cur[bb * 128 + 64 + lane]);
                float m = fmaxf(v0, v1);
#pragma unroll
                for (int d = 32; d > 0; d >>= 1) m = fmaxf(m, __shfl_xor(m, d));
                float e0 = expf(v0 - m), e1 = expf(v1 - m);
                float sum = e0 + e1;
#pragma unroll
                for (int d = 32; d > 0; d >>= 1) sum += __shfl_xor(sum, d);
                float inv = 1.f / sum;
                pT[lane][bb] = e0 * inv;
                pT[64 + lane][bb] = e1 * inv;
            }
        }
        __syncthreads();
        float c2v = 0.f;
        {
            int jjc = tid >> 5, bbc = tid & 31;
            if (tid < 256) {
#pragma unroll
                for (int ww = 0; ww < 8; ++ww) c2v += partc2[ww][jjc][bbc];
            }
        }
        {   // ctx partials: (jj, sh, b); 64 s each; Ft rows contiguous
            int jj = tid >> 6, sh = (tid >> 5) & 1, bb = tid & 31;
            const float* fr = Ft + (size_t)(j0 + jj) * 4096 + bb * 128 + 64 * sh;
            float ca = 0.f;
#pragma unroll
            for (int qq = 0; qq < 16; ++qq) {
                float4 f4 = *(const float4*)(fr + 4 * qq);
                int sb = 64 * sh + 4 * qq;
                ca += f4.x * pT[sb][bb] + f4.y * pT[sb + 1][bb]
                    + f4.z * pT[sb + 2][bb] + f4.w * pT[sb + 3][bb];
            }
            ctxp[jj][sh][bb] = ca;
        }
        // seed next step's score buffer with gbias (blocks 0..31 cover 32x128)
        if (bid < 32 && tid < 128)
            st1cg(&Sc_nxt[bid * 128 + tid], gbias[bid * 128 + tid]);
        __syncthreads();
        if (tid < 256) {
            int jj = tid >> 5, bb = tid & 31;
            float u = c2v + ctxp[jj][0][bb] + ctxp[jj][1][bb] + bcv;
            st1cg(&Ha[bb * 768 + j0 + jj], tanhf_(u));
        }
        grid_barrier(bar, target); target += NBLK;
    }
}

// ---------------------------------------------------------------------------
// workspace layout (bytes), peak ~71.03MB:
//   0         gi      14155776   (dead after seq -> Wpredb alias)
//   14155776  G       12582912   (dead after transpose G->Gt)
//   26738688  F       12582912   -- Gt [768][4096] aliases F after transposes
//   39321600  xh       2359296
//   41680896  xl       2359296
//   44040192  wihh     3538944
//   47579136  wihl     3538944
//   51118080  eh       6291456   -- Ft [768][4096] aliases eh+el after gemms
//   57409536  el       6291456
//   63700992  wath     1179648
//   64880640  watl     1179648
//   66060288  wc1h     1179648
//   67239936  wc1l     1179648
//   68419584  Hseq     2359296   (bf16)
//   70778880  gbias      16384
//   70795264  Ha         98304
//   70893568  Hb         98304
//   70991872  Sc         32768   (2x ping-pong 16KB)
//   71024640  bar         1024   (8 x 128B-spread counters)
// ---------------------------------------------------------------------------
extern "C" void kernel_launch(void* const* d_in, const int* in_sizes, int n_in,
                              void* d_out, int out_size, void* d_ws, size_t ws_size,
                              hipStream_t stream)
{
    const float* x      = (const float*)d_in[0];
    const float* h0     = (const float*)d_in[1];
    const float* E      = (const float*)d_in[2];
    const float* W_ih   = (const float*)d_in[3];
    const float* W_hh   = (const float*)d_in[4];
    const float* b_ih   = (const float*)d_in[5];
    const float* b_hh   = (const float*)d_in[6];
    const float* W_pred = (const float*)d_in[7];
    const float* b_pred = (const float*)d_in[8];
    const float* W_att  = (const float*)d_in[9];
    const float* b_att  = (const float*)d_in[10];
    const float* W_ctx  = (const float*)d_in[11];
    const float* b_ctx  = (const float*)d_in[12];
    float* out = (float*)d_out;

    char* ws = (char*)d_ws;
    float* gi    = (float*)(ws);
    float* G     = (float*)(ws + 14155776);
    float* F     = (float*)(ws + 26738688);
    bf16*  xh    = (bf16*)(ws + 39321600);
    bf16*  xl    = (bf16*)(ws + 41680896);
    bf16*  wihh  = (bf16*)(ws + 44040192);
    bf16*  wihl  = (bf16*)(ws + 47579136);
    bf16*  eh    = (bf16*)(ws + 51118080);
    bf16*  el    = (bf16*)(ws + 57409536);
    bf16*  wath  = (bf16*)(ws + 63700992);
    bf16*  watl  = (bf16*)(ws + 64880640);
    bf16*  wc1h  = (bf16*)(ws + 66060288);
    bf16*  wc1l  = (bf16*)(ws + 67239936);
    bf16*  Hseq  = (bf16*)(ws + 68419584);
    float* gbias = (float*)(ws + 70778880);
    float* Ha    = (float*)(ws + 70795264);
    float* Hb    = (float*)(ws + 70893568);
    float* Sc    = (float*)(ws + 70991872);
    unsigned int* bar = (unsigned int*)(ws + 71024640);
    float* Ft    = (float*)(ws + 51118080);   // aliases eh/el (dead by then)
    float* Gt    = (float*)(ws + 26738688);   // aliases F (dead after its transpose)
    bf16*  Wpredb = (bf16*)(ws);              // aliases dead gi/G/Gt/xh/xl

    hipMemsetAsync(bar, 0, NBARL * 32 * 4, stream);  // counters fresh each replay

    // 1. splits / b_att fold (also seeds Sc ping 0 with gbias)
    split_ops<<<8832, 256, 0, stream>>>(x, W_ih, E, W_ctx, W_att,
                                        xh, xl, wihh, wihl, eh, el,
                                        wc1h, wc1l, wath, watl);
    gbias_k<<<1024, 256, 0, stream>>>(E, b_att, gbias, Sc);

    // 2. near-f32 precompute GEMMs (split-bf16, f32 out)
    gemm_split<<<dim3(18, 12), 256, 0, stream>>>(
        xh, xl, 768, wihh, wihl, 768, b_ih, gi, 2304, BB * TT, 2304, 768);
    gemm_split<<<dim3(6, 32), 256, 0, stream>>>(
        eh, el, 768, wath, watl, 768, nullptr, G, 768, BB * SS, 768, 768);
    gemm_split<<<dim3(6, 32), 256, 0, stream>>>(
        eh, el, 768, wc1h, wc1l, 768, nullptr, F, 768, BB * SS, 768, 768);
    transpose_f<<<dim3(128, 24), 256, 0, stream>>>(F, Ft);   // F -> Ft (eh/el region)
    transpose_f<<<dim3(128, 24), 256, 0, stream>>>(G, Gt);   // G -> Gt (F region)

    // 3. all-CU sequential recurrence (f32 path, 2 fence-free barriers/step)
    seq_coop<<<NBLK, 512, 0, stream>>>(gi, Gt, Ft, gbias, h0, W_hh, W_ctx,
                                       b_hh, b_ctx, Ha, Hb, Sc, bar, Hseq);

    // 4. W_pred -> bf16 (into now-dead region), then logits GEMM (f32 out)
    conv_pred<<<21747, 256, 0, stream>>>(W_pred, Wpredb);
    gemm_bt<<<dim3(227, 12), 256, 0, stream>>>(
        Hseq, 768, Wpredb, 768, b_pred, out, VV, BB * TT, VV, 768);
}

// Round 4
// 3085.089 us; speedup vs baseline: 1.3983x; 1.3983x over previous
//
#include <hip/hip_runtime.h>
#include <hip/hip_bf16.h>

using bf16 = __hip_bfloat16;

typedef __attribute__((ext_vector_type(8))) short short8;   // 8 bf16 (4 VGPRs) MFMA frag
typedef __attribute__((ext_vector_type(4))) float floatx4;  // MFMA accumulator

#define BB 32
#define TT 48
#define SS 128
#define HH 768
#define VV 28996

__device__ __forceinline__ float sigmoidf_(float x) { return 1.0f / (1.0f + expf(-x)); }
__device__ __forceinline__ float tanhf_(float x) {
    float xx = fminf(fmaxf(x, -15.0f), 15.0f);
    float e = expf(2.0f * xx);
    return (e - 1.0f) / (e + 1.0f);
}

// ---------------------------------------------------------------------------
// Coherent (cross-XCD) helpers: agent-scope relaxed atomics compile to
// sc1-flagged global ops that bypass the non-coherent per-XCD L2 and are
// served by the LLC. No cache-wide fences needed anywhere.
// ---------------------------------------------------------------------------
__device__ __forceinline__ float ld1cg(const float* p) {
    return __hip_atomic_load((float*)p, __ATOMIC_RELAXED, __HIP_MEMORY_SCOPE_AGENT);
}
__device__ __forceinline__ float2 ld2cg(const float* p) {
    unsigned long long u = __hip_atomic_load((unsigned long long*)p,
                                             __ATOMIC_RELAXED, __HIP_MEMORY_SCOPE_AGENT);
    union { unsigned long long u; float2 f; } c; c.u = u; return c.f;
}
__device__ __forceinline__ void st1cg(float* p, float v) {
    __hip_atomic_store(p, v, __ATOMIC_RELAXED, __HIP_MEMORY_SCOPE_AGENT);
}

// ---------------------------------------------------------------------------
// Split f32 -> bf16 hi + bf16 lo (lo = rounded residual); combined ~2^-17 rel.
// ---------------------------------------------------------------------------
__device__ __forceinline__ void split1(float v, bf16& h, bf16& l) {
    h = (bf16)v;
    l = (bf16)(v - __bfloat162float(h));
}

// counts (in float4 quads unless noted)
#define XQ    294912   // x:    1536*768/4
#define WIHQ  442368   // Wih:  2304*768/4
#define EQ    786432   // E:    4096*768/4
#define WC1Q  147456   // Wc1:  768*768/4 (compacted from W_ctx[:, :768])
#define WATS  589824   // WatT: 768*768 scalars (transpose)

__global__ __launch_bounds__(256)
void split_ops(const float* __restrict__ x, const float* __restrict__ Wih,
               const float* __restrict__ E, const float* __restrict__ Wctx,
               const float* __restrict__ Watt,
               bf16* __restrict__ xh, bf16* __restrict__ xl,
               bf16* __restrict__ wihh, bf16* __restrict__ wihl,
               bf16* __restrict__ eh, bf16* __restrict__ el,
               bf16* __restrict__ wc1h, bf16* __restrict__ wc1l,
               bf16* __restrict__ wath, bf16* __restrict__ watl)
{
    int idx = blockIdx.x * 256 + threadIdx.x;
    if (idx < XQ + WIHQ + EQ) {
        const float* src; bf16 *dh, *dl; int off;
        if (idx < XQ)            { src = x;   dh = xh;   dl = xl;   off = idx; }
        else if (idx < XQ + WIHQ){ src = Wih; dh = wihh; dl = wihl; off = idx - XQ; }
        else                     { src = E;   dh = eh;   dl = el;   off = idx - XQ - WIHQ; }
        float4 v = ((const float4*)src)[off];
        union { bf16 b[4]; uint2 u; } oh, ol;
        split1(v.x, oh.b[0], ol.b[0]); split1(v.y, oh.b[1], ol.b[1]);
        split1(v.z, oh.b[2], ol.b[2]); split1(v.w, oh.b[3], ol.b[3]);
        ((uint2*)dh)[off] = oh.u; ((uint2*)dl)[off] = ol.u;
    } else if (idx < XQ + WIHQ + EQ + WC1Q) {
        int rem = idx - XQ - WIHQ - EQ;          // j*192 + c4
        int j = rem / 192, c4 = rem - j * 192;
        float4 v = *(const float4*)(Wctx + (size_t)j * 1536 + 4 * c4);
        union { bf16 b[4]; uint2 u; } oh, ol;
        split1(v.x, oh.b[0], ol.b[0]); split1(v.y, oh.b[1], ol.b[1]);
        split1(v.z, oh.b[2], ol.b[2]); split1(v.w, oh.b[3], ol.b[3]);
        ((uint2*)wc1h)[rem] = oh.u; ((uint2*)wc1l)[rem] = ol.u;
    } else if (idx < XQ + WIHQ + EQ + WC1Q + WATS) {
        int rem = idx - XQ - WIHQ - EQ - WC1Q;   // n*768 + k
        int n = rem / 768, k = rem - n * 768;
        float v = Watt[(size_t)k * 768 + n];     // WatT[n][k] = W_att[k][n]
        bf16 h, l; split1(v, h, l);
        wath[rem] = h; watl[rem] = l;
    }
}

// gbias[b*S+s] = b_att . E[b,s,:]
__global__ __launch_bounds__(256)
void gbias_k(const float* __restrict__ E, const float* __restrict__ batt,
             float* __restrict__ gbias)
{
    int row = blockIdx.x * 4 + (threadIdx.x >> 6);
    int lane = threadIdx.x & 63;
    const float* er = E + (size_t)row * 768;
    float acc = 0.f;
#pragma unroll
    for (int i = 0; i < 12; ++i) acc += er[i * 64 + lane] * batt[i * 64 + lane];
#pragma unroll
    for (int d = 32; d > 0; d >>= 1) acc += __shfl_xor(acc, d);
    if (lane == 0) gbias[row] = acc;
}

// W_pred f32 -> bf16 (logits operand; off the recurrent path, bf16 is safe)
#define WPQ 5567232   // 28996*768/4
__global__ __launch_bounds__(256)
void conv_pred(const float* __restrict__ Wp, bf16* __restrict__ Wpb)
{
    int idx = blockIdx.x * 256 + threadIdx.x;
    if (idx >= WPQ) return;
    float4 v = ((const float4*)Wp)[idx];
    union { bf16 b[4]; uint2 u; } o;
    o.b[0] = (bf16)v.x; o.b[1] = (bf16)v.y; o.b[2] = (bf16)v.z; o.b[3] = (bf16)v.w;
    ((uint2*)Wpb)[idx] = o.u;
}

// ---------------------------------------------------------------------------
// Split-bf16 near-f32 GEMM: C[m,n] = sum_k A[m,k]*B[n,k] (+bias[n]), f32 out.
// ---------------------------------------------------------------------------
__global__ __launch_bounds__(256)
void gemm_split(const bf16* __restrict__ Ahi, const bf16* __restrict__ Alo, int lda,
                const bf16* __restrict__ Bhi, const bf16* __restrict__ Blo, int ldb,
                const float* __restrict__ bias,
                float* __restrict__ C, int ldc, int M, int N, int K)
{
    __shared__ __align__(16) char smem[65536];  // Ahi|Alo|Bhi|Blo 16KB each
    const int tid  = threadIdx.x;
    const int lane = tid & 63;
    const int widx = tid >> 6;
    const int wm = widx >> 1, wn = widx & 1;
    const int m0 = blockIdx.y * 128, n0 = blockIdx.x * 128;

    floatx4 acc[4][4];
    const floatx4 fzero = {0.f, 0.f, 0.f, 0.f};
#pragma unroll
    for (int i = 0; i < 4; ++i)
#pragma unroll
        for (int j = 0; j < 4; ++j) acc[i][j] = fzero;

    const int srow = tid >> 3, sslot = tid & 7;

    for (int kb = 0; kb < K; kb += 64) {
        __syncthreads();
        const bf16* mats[4] = {Ahi, Alo, Bhi, Blo};
#pragma unroll
        for (int mt = 0; mt < 4; ++mt) {
            const bf16* base = mats[mt];
            int ld   = (mt < 2) ? lda : ldb;
            int row0 = (mt < 2) ? m0 : n0;
#pragma unroll
            for (int r = 0; r < 4; ++r) {
                int row = r * 32 + srow;
                int c = sslot ^ (row & 7);
                const bf16* gp = base + (size_t)(row0 + row) * ld + kb + c * 8;
                char* lp = smem + mt * 16384 + r * 4096 + widx * 1024;
                __builtin_amdgcn_global_load_lds(
                    (const __attribute__((address_space(1))) void*)gp,
                    (__attribute__((address_space(3))) void*)lp, 16, 0, 0);
            }
        }
        __syncthreads();
#pragma unroll
        for (int kc = 0; kc < 2; ++kc) {
            short8 ah[4], al[4], bh[4], bl[4];
#pragma unroll
            for (int i = 0; i < 4; ++i) {
                int mrow = wm * 64 + i * 16 + (lane & 15);
                int nrow = wn * 64 + i * 16 + (lane & 15);
                int ca = kc * 4 + (lane >> 4);
                int sm = (ca ^ (mrow & 7)) * 16, sn = (ca ^ (nrow & 7)) * 16;
                ah[i] = *(const short8*)(smem +         mrow * 128 + sm);
                al[i] = *(const short8*)(smem + 16384 + mrow * 128 + sm);
                bh[i] = *(const short8*)(smem + 32768 + nrow * 128 + sn);
                bl[i] = *(const short8*)(smem + 49152 + nrow * 128 + sn);
            }
#pragma unroll
            for (int i = 0; i < 4; ++i)
#pragma unroll
                for (int j = 0; j < 4; ++j) {
                    acc[i][j] = __builtin_amdgcn_mfma_f32_16x16x32_bf16(ah[i], bh[j], acc[i][j], 0, 0, 0);
                    acc[i][j] = __builtin_amdgcn_mfma_f32_16x16x32_bf16(ah[i], bl[j], acc[i][j], 0, 0, 0);
                    acc[i][j] = __builtin_amdgcn_mfma_f32_16x16x32_bf16(al[i], bh[j], acc[i][j], 0, 0, 0);
                }
        }
    }
#pragma unroll
    for (int i = 0; i < 4; ++i) {
        int gm0 = m0 + wm * 64 + i * 16 + (lane >> 4) * 4;
#pragma unroll
        for (int j = 0; j < 4; ++j) {
            int gn = n0 + wn * 64 + j * 16 + (lane & 15);
            float bv = bias ? bias[gn] : 0.0f;
#pragma unroll
            for (int r2 = 0; r2 < 4; ++r2)
                C[(size_t)(gm0 + r2) * ldc + gn] = acc[i][j][r2] + bv;
        }
    }
}

// ---------------------------------------------------------------------------
// Plain bf16 MFMA GEMM (m97-style) for the logits: f32 out, N edge handled.
// ---------------------------------------------------------------------------
__global__ __launch_bounds__(256)
void gemm_bt(const bf16* __restrict__ A, int lda,
             const bf16* __restrict__ Bm, int ldb,
             const float* __restrict__ bias,
             float* __restrict__ C, int ldc, int M, int N, int K)
{
    __shared__ __align__(16) char smem[32768];
    const int tid  = threadIdx.x;
    const int lane = tid & 63;
    const int widx = tid >> 6;
    const int wm = widx >> 1, wn = widx & 1;
    const int m0 = blockIdx.y * 128, n0 = blockIdx.x * 128;

    floatx4 acc[4][4];
    const floatx4 fzero = {0.f, 0.f, 0.f, 0.f};
#pragma unroll
    for (int i = 0; i < 4; ++i)
#pragma unroll
        for (int j = 0; j < 4; ++j) acc[i][j] = fzero;

    const int srow = tid >> 3, sslot = tid & 7;

    for (int kb = 0; kb < K; kb += 64) {
        __syncthreads();
#pragma unroll
        for (int r = 0; r < 4; ++r) {
            int mrow = r * 32 + srow;
            int c = sslot ^ (mrow & 7);
            const bf16* gp = A + (size_t)(m0 + mrow) * lda + kb + c * 8;
            char* lp = smem + r * 4096 + widx * 1024;
            __builtin_amdgcn_global_load_lds(
                (const __attribute__((address_space(1))) void*)gp,
                (__attribute__((address_space(3))) void*)lp, 16, 0, 0);
        }
#pragma unroll
        for (int r = 0; r < 4; ++r) {
            int nrow = r * 32 + srow;
            int gn = n0 + nrow; if (gn > N - 1) gn = N - 1;
            int c = sslot ^ (nrow & 7);
            const bf16* gp = Bm + (size_t)gn * ldb + kb + c * 8;
            char* lp = smem + 16384 + r * 4096 + widx * 1024;
            __builtin_amdgcn_global_load_lds(
                (const __attribute__((address_space(1))) void*)gp,
                (__attribute__((address_space(3))) void*)lp, 16, 0, 0);
        }
        __syncthreads();
#pragma unroll
        for (int kc = 0; kc < 2; ++kc) {
            short8 af[4], bfr[4];
#pragma unroll
            for (int i = 0; i < 4; ++i) {
                int mrow = wm * 64 + i * 16 + (lane & 15);
                int nrow = wn * 64 + i * 16 + (lane & 15);
                int ca = kc * 4 + (lane >> 4);
                af[i]  = *(const short8*)(smem +         mrow * 128 + ((ca ^ (mrow & 7)) * 16));
                bfr[i] = *(const short8*)(smem + 16384 + nrow * 128 + ((ca ^ (nrow & 7)) * 16));
            }
#pragma unroll
            for (int i = 0; i < 4; ++i)
#pragma unroll
                for (int j = 0; j < 4; ++j)
                    acc[i][j] = __builtin_amdgcn_mfma_f32_16x16x32_bf16(af[i], bfr[j], acc[i][j], 0, 0, 0);
        }
    }
#pragma unroll
    for (int i = 0; i < 4; ++i) {
        int gm0 = m0 + wm * 64 + i * 16 + (lane >> 4) * 4;
#pragma unroll
        for (int j = 0; j < 4; ++j) {
            int gn = n0 + wn * 64 + j * 16 + (lane & 15);
            if (gn < N) {
                float bv = bias ? bias[gn] : 0.0f;
#pragma unroll
                for (int r2 = 0; r2 < 4; ++r2)
                    C[(size_t)(gm0 + r2) * ldc + gn] = acc[i][j][r2] + bv;
            }
        }
    }
}

// ---------------------------------------------------------------------------
// F [4096][768] -> Ft [768][4096]  (j-major so phase C streams contiguously)
// ---------------------------------------------------------------------------
__global__ __launch_bounds__(256)
void transpose_f(const float* __restrict__ F, float* __restrict__ Ft)
{
    __shared__ float tile[32][33];
    int tx = threadIdx.x & 31, ty = threadIdx.x >> 5;  // ty<8
    int r0 = blockIdx.x << 5, j0 = blockIdx.y << 5;
#pragma unroll
    for (int i = 0; i < 4; ++i)
        tile[ty + 8 * i][tx] = F[(size_t)(r0 + ty + 8 * i) * 768 + j0 + tx];
    __syncthreads();
#pragma unroll
    for (int i = 0; i < 4; ++i)
        Ft[(size_t)(j0 + ty + 8 * i) * 4096 + r0 + tx] = tile[tx][ty + 8 * i];
}

// ---------------------------------------------------------------------------
// STORE-BASED flag barrier (no atomics, no fences). Each block owns one flag
// word (16-B spread => zero store contention, fire-and-forget). 96 threads
// of every block poll one flag each, in parallel: one coherent-load latency
// per poll round. __syncthreads() drains vmcnt(0) before the flag store, so
// all of the block's sc1 data stores are LLC-visible before its flag flips.
// Flags are monotonic step counters (memset once per graph replay).
// ---------------------------------------------------------------------------
#define NBLK 96
__device__ __forceinline__ void flag_barrier(unsigned int* flags, unsigned int target)
{
    __syncthreads();                    // all lanes' coherent stores are done
    if (threadIdx.x == 0)
        __hip_atomic_store(&flags[blockIdx.x * 4], target,
                           __ATOMIC_RELAXED, __HIP_MEMORY_SCOPE_AGENT);
    if (threadIdx.x < NBLK) {
        while (__hip_atomic_load(&flags[threadIdx.x * 4], __ATOMIC_RELAXED,
                                 __HIP_MEMORY_SCOPE_AGENT) < target)
            __builtin_amdgcn_s_sleep(1);
    }
    __syncthreads();
}

// ---------------------------------------------------------------------------
// All-CU sequential decoder v4. 96 blocks x 512 threads; block owns 8 hidden
// dims (32 weight rows in LDS ~96KB, loaded once). THREE cheap flag barriers
// per step:
//  A: gates matvec (coherent h_prev) -> h_t (write Hb)               -> bar
//  B: c2 matvec (coherent h_t) + this block's ~43 scores for batch
//     bid/3 (h_t[b] staged in LDS once, G row-major from L2)         -> bar
//  C: softmax (coherent Sc, redundant) + ctx (Ft) + h_new (write Ha) -> bar
// All recurrent math f32. Cross-block state only via sc1 LLC ops. NO atomics.
// ---------------------------------------------------------------------------
__global__ __launch_bounds__(512)
void seq_coop(const float* __restrict__ gi,     // [B*T][2304]
              const float* __restrict__ G,      // [B*S][768]
              const float* __restrict__ Ft,     // [768][B*S]
              const float* __restrict__ gbias,  // [B*S]
              const float* __restrict__ h0,     // [B][768]
              const float* __restrict__ Whh,    // [2304][768] (raw input)
              const float* __restrict__ Wctx,   // [768][1536] (raw input)
              const float* __restrict__ bhh,    // [2304]
              const float* __restrict__ bctx,   // [768]
              float* __restrict__ Ha,           // [32][768]  h_new (post-attn)
              float* __restrict__ Hb,           // [32][768]  h_t (post-GRU)
              float* __restrict__ Sc,           // [32][128]  raw scores
              unsigned int* __restrict__ flags,
              bf16* __restrict__ Hseq)          // [B*T][768]
{
    const int bid  = blockIdx.x;
    const int tid  = threadIdx.x;
    const int w    = tid >> 6;          // 8 waves
    const int lane = tid & 63;
    const int kg   = lane & 7;          // k sub-chunk within wave
    const int bo   = lane >> 3;         // batch offset: b = bo + 8q
    const int j0   = bid * 8;

    __shared__ __align__(16) float Wlds[32][768];   // rr = gate*8+jj (r,z,n), 24+jj (c2)
    __shared__ __align__(16) char  scr[24576];      // A: part[8][24][32]
                                                    // B: h_lds[768]
                                                    // C: pT[128][33] | ctxp[8][2][32]
    __shared__ float partc2[8][8][32];
    __shared__ float redsum[24][32];

    float (*part)[24][32] = (float (*)[24][32])scr;
    float* h_lds          = (float*)scr;
    float (*pT)[33]       = (float (*)[33])scr;
    float (*ctxp)[2][32]  = (float (*)[2][32])(scr + 16896);

    // ---- load the block's 32 weight rows into LDS (once) ----
    for (int idx = tid; idx < 32 * 768; idx += 512) {
        int rr = idx / 768, k = idx - rr * 768;
        float v;
        if (rr < 24) {
            int gate = rr >> 3, jj = rr & 7;
            v = Whh[(size_t)(gate * 768 + j0 + jj) * 768 + k];
        } else {
            int jj = rr - 24;
            v = Wctx[(size_t)(j0 + jj) * 1536 + 768 + k];
        }
        (&Wlds[0][0])[idx] = v;
    }

    // hoisted pointwise constants (threads 0..255: jj = tid>>5, b = tid&31)
    float bhr = 0.f, bhz = 0.f, bhn = 0.f, bcv = 0.f;
    if (tid < 256) {
        int jj = tid >> 5;
        bhr = bhh[j0 + jj]; bhz = bhh[768 + j0 + jj]; bhn = bhh[1536 + j0 + jj];
        bcv = bctx[j0 + jj];
    }
    const int k4b = 3 * (8 * w + kg);    // this lane's float4 k-chunk (x3)
    const int bstar = bid / 3;           // scores: this block's batch
    const int part_ = bid - 3 * bstar;   // s-slice index 0..2
    const int s_begin = part_ * 43;      // 0..43 / 43..86 / 86..128
    const int s_end   = (part_ == 2) ? 128 : s_begin + 43;

    unsigned int target = 1;
    __syncthreads();

#pragma unroll 1
    for (int t = 0; t < TT; ++t) {
        const float* hp = (t == 0) ? h0 : Ha;

        // early pointwise-input loads (latency hidden under the k-loop)
        float e_ir = 0.f, e_iz = 0.f, e_inn = 0.f, e_hprev = 0.f;
        if (tid < 256) {
            int jj = tid >> 5, bb = tid & 31;
            const float* gir = gi + (size_t)(bb * TT + t) * 2304 + j0 + jj;
            e_ir = gir[0]; e_iz = gir[768]; e_inn = gir[1536];
            e_hprev = ld1cg(hp + bb * 768 + j0 + jj);
        }

        // ---- Phase A: gates matvec, 24 rows (r,z,n) vs h_prev ----
        {
            const float* hp_b = hp + bo * 768 + 4 * k4b;
            float2 h2[4][6];
#pragma unroll
            for (int q = 0; q < 4; ++q) {
                const float* hq = hp_b + q * 8 * 768;
#pragma unroll
                for (int i = 0; i < 6; ++i) h2[q][i] = ld2cg(hq + 2 * i);
            }
#pragma unroll
            for (int half = 0; half < 2; ++half) {
                float acc[12][4];
#pragma unroll
                for (int r = 0; r < 12; ++r)
#pragma unroll
                    for (int q = 0; q < 4; ++q) acc[r][q] = 0.f;
#pragma unroll
                for (int r = 0; r < 12; ++r) {
                    const float* wr_ = &Wlds[half * 12 + r][4 * k4b];
#pragma unroll
                    for (int i = 0; i < 6; ++i) {
                        float2 w2 = *(const float2*)(wr_ + 2 * i);
#pragma unroll
                        for (int q = 0; q < 4; ++q)
                            acc[r][q] += w2.x * h2[q][i].x + w2.y * h2[q][i].y;
                    }
                }
#pragma unroll
                for (int r = 0; r < 12; ++r)
#pragma unroll
                    for (int q = 0; q < 4; ++q) {
                        float v = acc[r][q];
                        v += __shfl_xor(v, 1); v += __shfl_xor(v, 2); v += __shfl_xor(v, 4);
                        if (kg == 0) part[w][half * 12 + r][bo + 8 * q] = v;
                    }
            }
        }
        __syncthreads();
        for (int o = tid; o < 768; o += 512) {
            int rr = o >> 5, bb = o & 31;
            float s = 0.f;
#pragma unroll
            for (int ww = 0; ww < 8; ++ww) s += part[ww][rr][bb];
            redsum[rr][bb] = s;
        }
        __syncthreads();
        if (tid < 256) {
            int jj = tid >> 5, bb = tid & 31;
            float r = sigmoidf_(e_ir + redsum[jj][bb] + bhr);
            float z = sigmoidf_(e_iz + redsum[8 + jj][bb] + bhz);
            float n = tanhf_(e_inn + r * (redsum[16 + jj][bb] + bhn));
            float ht = (1.f - z) * n + z * e_hprev;
            st1cg(&Hb[bb * 768 + j0 + jj], ht);
            Hseq[(size_t)(bb * TT + t) * 768 + j0 + jj] = (bf16)ht;
        }
        flag_barrier(flags, target); ++target;

        // ---- Phase B: c2 matvec (coherent Hb) + this block's scores ----
        if (tid < 384) {                  // stage h_t[bstar] into LDS (coherent)
            float2 v = ld2cg(Hb + bstar * 768 + 2 * tid);
            h_lds[2 * tid] = v.x; h_lds[2 * tid + 1] = v.y;
        }
        {
            const float* hb_b = Hb + bo * 768 + 4 * k4b;
            float2 h2[4][6];
#pragma unroll
            for (int q = 0; q < 4; ++q) {
                const float* hq = hb_b + q * 8 * 768;
#pragma unroll
                for (int i = 0; i < 6; ++i) h2[q][i] = ld2cg(hq + 2 * i);
            }
            float a2[8][4];
#pragma unroll
            for (int r = 0; r < 8; ++r)
#pragma unroll
                for (int q = 0; q < 4; ++q) a2[r][q] = 0.f;
#pragma unroll
            for (int r = 0; r < 8; ++r) {
                const float* wr_ = &Wlds[24 + r][4 * k4b];
#pragma unroll
                for (int i = 0; i < 6; ++i) {
                    float2 w2 = *(const float2*)(wr_ + 2 * i);
#pragma unroll
                    for (int q = 0; q < 4; ++q)
                        a2[r][q] += w2.x * h2[q][i].x + w2.y * h2[q][i].y;
                }
            }
#pragma unroll
            for (int r = 0; r < 8; ++r)
#pragma unroll
                for (int q = 0; q < 4; ++q) {
                    float v = a2[r][q];
                    v += __shfl_xor(v, 1); v += __shfl_xor(v, 2); v += __shfl_xor(v, 4);
                    if (kg == 0) partc2[w][r][bo + 8 * q] = v;
                }
        }
        __syncthreads();                  // h_lds ready for score waves
        for (int s = s_begin + w; s < s_end; s += 8) {
            const float* grow = G + (size_t)(bstar * 128 + s) * 768;
            float sa = 0.f;
#pragma unroll
            for (int q = 0; q < 3; ++q) {
                int k4 = 4 * (q * 64 + lane);
                float4 g4 = *(const float4*)(grow + k4);
                sa += g4.x * h_lds[k4] + g4.y * h_lds[k4 + 1]
                    + g4.z * h_lds[k4 + 2] + g4.w * h_lds[k4 + 3];
            }
#pragma unroll
            for (int d = 32; d > 0; d >>= 1) sa += __shfl_xor(sa, d);
            if (lane == 0)
                st1cg(&Sc[bstar * 128 + s], sa + gbias[bstar * 128 + s]);
        }
        flag_barrier(flags, target); ++target;

        // ---- Phase C: softmax (redundant per block) + ctx + c2 + h_new ----
        {   // softmax: wave w -> batches 4w..4w+3 (coherent Sc reads)
#pragma unroll
            for (int q = 0; q < 4; ++q) {
                int bb = 4 * w + q;
                float v0 = ld1cg(&Sc[bb * 128 + lane]);
                float v1 = ld1cg(&Sc[bb * 128 + 64 + lane]);
                float m = fmaxf(v0, v1);
#pragma unroll
                for (int d = 32; d > 0; d >>= 1) m = fmaxf(m, __shfl_xor(m, d));
                float e0 = expf(v0 - m), e1 = expf(v1 - m);
                float sum = e0 + e1;
#pragma unroll
                for (int d = 32; d > 0; d >>= 1) sum += __shfl_xor(sum, d);
                float inv = 1.f / sum;
                pT[lane][bb] = e0 * inv;
                pT[64 + lane][bb] = e1 * inv;
            }
        }
        __syncthreads();
        float c2v = 0.f;
        if (tid < 256) {
            int jjc = tid >> 5, bbc = tid & 31;
#pragma unroll
            for (int ww = 0; ww < 8; ++ww) c2v += partc2[ww][jjc][bbc];
        }
        {   // ctx partials: (jj, sh, b); 64 s each; Ft rows contiguous
            int jj = tid >> 6, sh = (tid >> 5) & 1, bb = tid & 31;
            const float* fr = Ft + (size_t)(j0 + jj) * 4096 + bb * 128 + 64 * sh;
            float ca = 0.f;
#pragma unroll
            for (int qq = 0; qq < 16; ++qq) {
                float4 f4 = *(const float4*)(fr + 4 * qq);
                int sb = 64 * sh + 4 * qq;
                ca += f4.x * pT[sb][bb] + f4.y * pT[sb + 1][bb]
                    + f4.z * pT[sb + 2][bb] + f4.w * pT[sb + 3][bb];
            }
            ctxp[jj][sh][bb] = ca;
        }
        __syncthreads();
        if (tid < 256) {
            int jj = tid >> 5, bb = tid & 31;
            float u = c2v + ctxp[jj][0][bb] + ctxp[jj][1][bb] + bcv;
            st1cg(&Ha[bb * 768 + j0 + jj], tanhf_(u));
        }
        flag_barrier(flags, target); ++target;
    }
}

// ---------------------------------------------------------------------------
// workspace layout (bytes), peak ~71.01MB:
//   0         gi      14155776   (dead after seq -> Wpredb alias)
//   14155776  G       12582912   (live through seq; dead before conv_pred)
//   26738688  F       12582912   (dead after transpose F->Ft)
//   39321600  xh       2359296
//   41680896  xl       2359296
//   44040192  wihh     3538944
//   47579136  wihl     3538944
//   51118080  eh       6291456   -- Ft [768][4096] aliases eh+el after gemms
//   57409536  el       6291456
//   63700992  wath     1179648
//   64880640  watl     1179648
//   66060288  wc1h     1179648
//   67239936  wc1l     1179648
//   68419584  Hseq     2359296   (bf16)
//   70778880  gbias      16384
//   70795264  Ha         98304
//   70893568  Hb         98304
//   70991872  Sc         16384
//   71008256  flags       1536   (96 x 16B-spread flag words)
// ---------------------------------------------------------------------------
extern "C" void kernel_launch(void* const* d_in, const int* in_sizes, int n_in,
                              void* d_out, int out_size, void* d_ws, size_t ws_size,
                              hipStream_t stream)
{
    const float* x      = (const float*)d_in[0];
    const float* h0     = (const float*)d_in[1];
    const float* E      = (const float*)d_in[2];
    const float* W_ih   = (const float*)d_in[3];
    const float* W_hh   = (const float*)d_in[4];
    const float* b_ih   = (const float*)d_in[5];
    const float* b_hh   = (const float*)d_in[6];
    const float* W_pred = (const float*)d_in[7];
    const float* b_pred = (const float*)d_in[8];
    const float* W_att  = (const float*)d_in[9];
    const float* b_att  = (const float*)d_in[10];
    const float* W_ctx  = (const float*)d_in[11];
    const float* b_ctx  = (const float*)d_in[12];
    float* out = (float*)d_out;

    char* ws = (char*)d_ws;
    float* gi    = (float*)(ws);
    float* G     = (float*)(ws + 14155776);
    float* F     = (float*)(ws + 26738688);
    bf16*  xh    = (bf16*)(ws + 39321600);
    bf16*  xl    = (bf16*)(ws + 41680896);
    bf16*  wihh  = (bf16*)(ws + 44040192);
    bf16*  wihl  = (bf16*)(ws + 47579136);
    bf16*  eh    = (bf16*)(ws + 51118080);
    bf16*  el    = (bf16*)(ws + 57409536);
    bf16*  wath  = (bf16*)(ws + 63700992);
    bf16*  watl  = (bf16*)(ws + 64880640);
    bf16*  wc1h  = (bf16*)(ws + 66060288);
    bf16*  wc1l  = (bf16*)(ws + 67239936);
    bf16*  Hseq  = (bf16*)(ws + 68419584);
    float* gbias = (float*)(ws + 70778880);
    float* Ha    = (float*)(ws + 70795264);
    float* Hb    = (float*)(ws + 70893568);
    float* Sc    = (float*)(ws + 70991872);
    unsigned int* flags = (unsigned int*)(ws + 71008256);
    float* Ft    = (float*)(ws + 51118080);   // aliases eh/el (dead by then)
    bf16*  Wpredb = (bf16*)(ws);              // aliases dead gi/G/F/xh/xl

    hipMemsetAsync(flags, 0, NBLK * 16, stream);  // flags fresh each replay

    // 1. splits / b_att fold
    split_ops<<<8832, 256, 0, stream>>>(x, W_ih, E, W_ctx, W_att,
                                        xh, xl, wihh, wihl, eh, el,
                                        wc1h, wc1l, wath, watl);
    gbias_k<<<1024, 256, 0, stream>>>(E, b_att, gbias);

    // 2. near-f32 precompute GEMMs (split-bf16, f32 out)
    gemm_split<<<dim3(18, 12), 256, 0, stream>>>(
        xh, xl, 768, wihh, wihl, 768, b_ih, gi, 2304, BB * TT, 2304, 768);
    gemm_split<<<dim3(6, 32), 256, 0, stream>>>(
        eh, el, 768, wath, watl, 768, nullptr, G, 768, BB * SS, 768, 768);
    gemm_split<<<dim3(6, 32), 256, 0, stream>>>(
        eh, el, 768, wc1h, wc1l, 768, nullptr, F, 768, BB * SS, 768, 768);
    transpose_f<<<dim3(128, 24), 256, 0, stream>>>(F, Ft);   // F -> Ft

    // 3. all-CU sequential recurrence (f32 path, 3 store-flag barriers/step)
    seq_coop<<<NBLK, 512, 0, stream>>>(gi, G, Ft, gbias, h0, W_hh, W_ctx,
                                       b_hh, b_ctx, Ha, Hb, Sc, flags, Hseq);

    // 4. W_pred -> bf16 (into now-dead region), then logits GEMM (f32 out)
    conv_pred<<<21747, 256, 0, stream>>>(W_pred, Wpredb);
    gemm_bt<<<dim3(227, 12), 256, 0, stream>>>(
        Hseq, 768, Wpredb, 768, b_pred, out, VV, BB * TT, VV, 768);
}

// Round 6
// 2088.596 us; speedup vs baseline: 2.0655x; 1.4771x over previous
//
#include <hip/hip_runtime.h>
#include <hip/hip_bf16.h>

using bf16 = __hip_bfloat16;

typedef __attribute__((ext_vector_type(8))) short short8;   // 8 bf16 (4 VGPRs) MFMA frag
typedef __attribute__((ext_vector_type(4))) float floatx4;  // MFMA accumulator

#define BB 32
#define TT 48
#define SS 128
#define HH 768
#define VV 28996

__device__ __forceinline__ float sigmoidf_(float x) { return 1.0f / (1.0f + expf(-x)); }
__device__ __forceinline__ float tanhf_(float x) {
    float xx = fminf(fmaxf(x, -15.0f), 15.0f);
    float e = expf(2.0f * xx);
    return (e - 1.0f) / (e + 1.0f);
}

// ---------------------------------------------------------------------------
// Coherent (cross-XCD) helpers: agent-scope relaxed atomics compile to
// sc1-flagged global ops that bypass the non-coherent per-XCD L2 and are
// served by the LLC. No cache-wide fences needed anywhere.
// ---------------------------------------------------------------------------
__device__ __forceinline__ float ld1cg(const float* p) {
    return __hip_atomic_load((float*)p, __ATOMIC_RELAXED, __HIP_MEMORY_SCOPE_AGENT);
}
__device__ __forceinline__ float2 ld2cg(const float* p) {
    unsigned long long u = __hip_atomic_load((unsigned long long*)p,
                                             __ATOMIC_RELAXED, __HIP_MEMORY_SCOPE_AGENT);
    union { unsigned long long u; float2 f; } c; c.u = u; return c.f;
}
__device__ __forceinline__ void st1cg(float* p, float v) {
    __hip_atomic_store(p, v, __ATOMIC_RELAXED, __HIP_MEMORY_SCOPE_AGENT);
}

// ---------------------------------------------------------------------------
// Split f32 -> bf16 hi + bf16 lo (lo = rounded residual); combined ~2^-17 rel.
// ---------------------------------------------------------------------------
__device__ __forceinline__ void split1(float v, bf16& h, bf16& l) {
    h = (bf16)v;
    l = (bf16)(v - __bfloat162float(h));
}

// counts (in float4 quads unless noted)
#define XQ    294912   // x:    1536*768/4
#define WIHQ  442368   // Wih:  2304*768/4
#define EQ    786432   // E:    4096*768/4
#define WC1Q  147456   // Wc1:  768*768/4 (compacted from W_ctx[:, :768])
#define WATS  589824   // WatT: 768*768 scalars (transpose)

__global__ __launch_bounds__(256)
void split_ops(const float* __restrict__ x, const float* __restrict__ Wih,
               const float* __restrict__ E, const float* __restrict__ Wctx,
               const float* __restrict__ Watt,
               bf16* __restrict__ xh, bf16* __restrict__ xl,
               bf16* __restrict__ wihh, bf16* __restrict__ wihl,
               bf16* __restrict__ eh, bf16* __restrict__ el,
               bf16* __restrict__ wc1h, bf16* __restrict__ wc1l,
               bf16* __restrict__ wath, bf16* __restrict__ watl)
{
    int idx = blockIdx.x * 256 + threadIdx.x;
    if (idx < XQ + WIHQ + EQ) {
        const float* src; bf16 *dh, *dl; int off;
        if (idx < XQ)            { src = x;   dh = xh;   dl = xl;   off = idx; }
        else if (idx < XQ + WIHQ){ src = Wih; dh = wihh; dl = wihl; off = idx - XQ; }
        else                     { src = E;   dh = eh;   dl = el;   off = idx - XQ - WIHQ; }
        float4 v = ((const float4*)src)[off];
        union { bf16 b[4]; uint2 u; } oh, ol;
        split1(v.x, oh.b[0], ol.b[0]); split1(v.y, oh.b[1], ol.b[1]);
        split1(v.z, oh.b[2], ol.b[2]); split1(v.w, oh.b[3], ol.b[3]);
        ((uint2*)dh)[off] = oh.u; ((uint2*)dl)[off] = ol.u;
    } else if (idx < XQ + WIHQ + EQ + WC1Q) {
        int rem = idx - XQ - WIHQ - EQ;          // j*192 + c4
        int j = rem / 192, c4 = rem - j * 192;
        float4 v = *(const float4*)(Wctx + (size_t)j * 1536 + 4 * c4);
        union { bf16 b[4]; uint2 u; } oh, ol;
        split1(v.x, oh.b[0], ol.b[0]); split1(v.y, oh.b[1], ol.b[1]);
        split1(v.z, oh.b[2], ol.b[2]); split1(v.w, oh.b[3], ol.b[3]);
        ((uint2*)wc1h)[rem] = oh.u; ((uint2*)wc1l)[rem] = ol.u;
    } else if (idx < XQ + WIHQ + EQ + WC1Q + WATS) {
        int rem = idx - XQ - WIHQ - EQ - WC1Q;   // n*768 + k
        int n = rem / 768, k = rem - n * 768;
        float v = Watt[(size_t)k * 768 + n];     // WatT[n][k] = W_att[k][n]
        bf16 h, l; split1(v, h, l);
        wath[rem] = h; watl[rem] = l;
    }
}

// gbias[b*S+s] = b_att . E[b,s,:]
__global__ __launch_bounds__(256)
void gbias_k(const float* __restrict__ E, const float* __restrict__ batt,
             float* __restrict__ gbias)
{
    int row = blockIdx.x * 4 + (threadIdx.x >> 6);
    int lane = threadIdx.x & 63;
    const float* er = E + (size_t)row * 768;
    float acc = 0.f;
#pragma unroll
    for (int i = 0; i < 12; ++i) acc += er[i * 64 + lane] * batt[i * 64 + lane];
#pragma unroll
    for (int d = 32; d > 0; d >>= 1) acc += __shfl_xor(acc, d);
    if (lane == 0) gbias[row] = acc;
}

// W_pred f32 -> bf16 (logits operand; off the recurrent path, bf16 is safe)
#define WPQ 5567232   // 28996*768/4
__global__ __launch_bounds__(256)
void conv_pred(const float* __restrict__ Wp, bf16* __restrict__ Wpb)
{
    int idx = blockIdx.x * 256 + threadIdx.x;
    if (idx >= WPQ) return;
    float4 v = ((const float4*)Wp)[idx];
    union { bf16 b[4]; uint2 u; } o;
    o.b[0] = (bf16)v.x; o.b[1] = (bf16)v.y; o.b[2] = (bf16)v.z; o.b[3] = (bf16)v.w;
    ((uint2*)Wpb)[idx] = o.u;
}

// ---------------------------------------------------------------------------
// Split-bf16 near-f32 GEMM: C[m,n] = sum_k A[m,k]*B[n,k] (+bias[n]), f32 out.
// ---------------------------------------------------------------------------
__global__ __launch_bounds__(256)
void gemm_split(const bf16* __restrict__ Ahi, const bf16* __restrict__ Alo, int lda,
                const bf16* __restrict__ Bhi, const bf16* __restrict__ Blo, int ldb,
                const float* __restrict__ bias,
                float* __restrict__ C, int ldc, int M, int N, int K)
{
    __shared__ __align__(16) char smem[65536];  // Ahi|Alo|Bhi|Blo 16KB each
    const int tid  = threadIdx.x;
    const int lane = tid & 63;
    const int widx = tid >> 6;
    const int wm = widx >> 1, wn = widx & 1;
    const int m0 = blockIdx.y * 128, n0 = blockIdx.x * 128;

    floatx4 acc[4][4];
    const floatx4 fzero = {0.f, 0.f, 0.f, 0.f};
#pragma unroll
    for (int i = 0; i < 4; ++i)
#pragma unroll
        for (int j = 0; j < 4; ++j) acc[i][j] = fzero;

    const int srow = tid >> 3, sslot = tid & 7;

    for (int kb = 0; kb < K; kb += 64) {
        __syncthreads();
        const bf16* mats[4] = {Ahi, Alo, Bhi, Blo};
#pragma unroll
        for (int mt = 0; mt < 4; ++mt) {
            const bf16* base = mats[mt];
            int ld   = (mt < 2) ? lda : ldb;
            int row0 = (mt < 2) ? m0 : n0;
#pragma unroll
            for (int r = 0; r < 4; ++r) {
                int row = r * 32 + srow;
                int c = sslot ^ (row & 7);
                const bf16* gp = base + (size_t)(row0 + row) * ld + kb + c * 8;
                char* lp = smem + mt * 16384 + r * 4096 + widx * 1024;
                __builtin_amdgcn_global_load_lds(
                    (const __attribute__((address_space(1))) void*)gp,
                    (__attribute__((address_space(3))) void*)lp, 16, 0, 0);
            }
        }
        __syncthreads();
#pragma unroll
        for (int kc = 0; kc < 2; ++kc) {
            short8 ah[4], al[4], bh[4], bl[4];
#pragma unroll
            for (int i = 0; i < 4; ++i) {
                int mrow = wm * 64 + i * 16 + (lane & 15);
                int nrow = wn * 64 + i * 16 + (lane & 15);
                int ca = kc * 4 + (lane >> 4);
                int sm = (ca ^ (mrow & 7)) * 16, sn = (ca ^ (nrow & 7)) * 16;
                ah[i] = *(const short8*)(smem +         mrow * 128 + sm);
                al[i] = *(const short8*)(smem + 16384 + mrow * 128 + sm);
                bh[i] = *(const short8*)(smem + 32768 + nrow * 128 + sn);
                bl[i] = *(const short8*)(smem + 49152 + nrow * 128 + sn);
            }
#pragma unroll
            for (int i = 0; i < 4; ++i)
#pragma unroll
                for (int j = 0; j < 4; ++j) {
                    acc[i][j] = __builtin_amdgcn_mfma_f32_16x16x32_bf16(ah[i], bh[j], acc[i][j], 0, 0, 0);
                    acc[i][j] = __builtin_amdgcn_mfma_f32_16x16x32_bf16(ah[i], bl[j], acc[i][j], 0, 0, 0);
                    acc[i][j] = __builtin_amdgcn_mfma_f32_16x16x32_bf16(al[i], bh[j], acc[i][j], 0, 0, 0);
                }
        }
    }
#pragma unroll
    for (int i = 0; i < 4; ++i) {
        int gm0 = m0 + wm * 64 + i * 16 + (lane >> 4) * 4;
#pragma unroll
        for (int j = 0; j < 4; ++j) {
            int gn = n0 + wn * 64 + j * 16 + (lane & 15);
            float bv = bias ? bias[gn] : 0.0f;
#pragma unroll
            for (int r2 = 0; r2 < 4; ++r2)
                C[(size_t)(gm0 + r2) * ldc + gn] = acc[i][j][r2] + bv;
        }
    }
}

// ---------------------------------------------------------------------------
// Plain bf16 MFMA GEMM (m97-style) for the logits: f32 out, N edge handled.
// ---------------------------------------------------------------------------
__global__ __launch_bounds__(256)
void gemm_bt(const bf16* __restrict__ A, int lda,
             const bf16* __restrict__ Bm, int ldb,
             const float* __restrict__ bias,
             float* __restrict__ C, int ldc, int M, int N, int K)
{
    __shared__ __align__(16) char smem[32768];
    const int tid  = threadIdx.x;
    const int lane = tid & 63;
    const int widx = tid >> 6;
    const int wm = widx >> 1, wn = widx & 1;
    const int m0 = blockIdx.y * 128, n0 = blockIdx.x * 128;

    floatx4 acc[4][4];
    const floatx4 fzero = {0.f, 0.f, 0.f, 0.f};
#pragma unroll
    for (int i = 0; i < 4; ++i)
#pragma unroll
        for (int j = 0; j < 4; ++j) acc[i][j] = fzero;

    const int srow = tid >> 3, sslot = tid & 7;

    for (int kb = 0; kb < K; kb += 64) {
        __syncthreads();
#pragma unroll
        for (int r = 0; r < 4; ++r) {
            int mrow = r * 32 + srow;
            int c = sslot ^ (mrow & 7);
            const bf16* gp = A + (size_t)(m0 + mrow) * lda + kb + c * 8;
            char* lp = smem + r * 4096 + widx * 1024;
            __builtin_amdgcn_global_load_lds(
                (const __attribute__((address_space(1))) void*)gp,
                (__attribute__((address_space(3))) void*)lp, 16, 0, 0);
        }
#pragma unroll
        for (int r = 0; r < 4; ++r) {
            int nrow = r * 32 + srow;
            int gn = n0 + nrow; if (gn > N - 1) gn = N - 1;
            int c = sslot ^ (nrow & 7);
            const bf16* gp = Bm + (size_t)gn * ldb + kb + c * 8;
            char* lp = smem + 16384 + r * 4096 + widx * 1024;
            __builtin_amdgcn_global_load_lds(
                (const __attribute__((address_space(1))) void*)gp,
                (__attribute__((address_space(3))) void*)lp, 16, 0, 0);
        }
        __syncthreads();
#pragma unroll
        for (int kc = 0; kc < 2; ++kc) {
            short8 af[4], bfr[4];
#pragma unroll
            for (int i = 0; i < 4; ++i) {
                int mrow = wm * 64 + i * 16 + (lane & 15);
                int nrow = wn * 64 + i * 16 + (lane & 15);
                int ca = kc * 4 + (lane >> 4);
                af[i]  = *(const short8*)(smem +         mrow * 128 + ((ca ^ (mrow & 7)) * 16));
                bfr[i] = *(const short8*)(smem + 16384 + nrow * 128 + ((ca ^ (nrow & 7)) * 16));
            }
#pragma unroll
            for (int i = 0; i < 4; ++i)
#pragma unroll
                for (int j = 0; j < 4; ++j)
                    acc[i][j] = __builtin_amdgcn_mfma_f32_16x16x32_bf16(af[i], bfr[j], acc[i][j], 0, 0, 0);
        }
    }
#pragma unroll
    for (int i = 0; i < 4; ++i) {
        int gm0 = m0 + wm * 64 + i * 16 + (lane >> 4) * 4;
#pragma unroll
        for (int j = 0; j < 4; ++j) {
            int gn = n0 + wn * 64 + j * 16 + (lane & 15);
            if (gn < N) {
                float bv = bias ? bias[gn] : 0.0f;
#pragma unroll
                for (int r2 = 0; r2 < 4; ++r2)
                    C[(size_t)(gm0 + r2) * ldc + gn] = acc[i][j][r2] + bv;
            }
        }
    }
}

// ---------------------------------------------------------------------------
// F [4096][768] -> Ft [768][4096]  (j-major so phase C streams contiguously)
// ---------------------------------------------------------------------------
__global__ __launch_bounds__(256)
void transpose_f(const float* __restrict__ F, float* __restrict__ Ft)
{
    __shared__ float tile[32][33];
    int tx = threadIdx.x & 31, ty = threadIdx.x >> 5;  // ty<8
    int r0 = blockIdx.x << 5, j0 = blockIdx.y << 5;
#pragma unroll
    for (int i = 0; i < 4; ++i)
        tile[ty + 8 * i][tx] = F[(size_t)(r0 + ty + 8 * i) * 768 + j0 + tx];
    __syncthreads();
#pragma unroll
    for (int i = 0; i < 4; ++i)
        Ft[(size_t)(j0 + ty + 8 * i) * 4096 + r0 + tx] = tile[tx][ty + 8 * i];
}

// ---------------------------------------------------------------------------
// STORE-BASED flag barrier (no atomics, no fences). Each block owns one flag
// word (16-B spread => zero store contention, fire-and-forget). 256 threads
// of every block poll one flag each, in parallel: one coherent-load latency
// per poll round instead of a serialized RMW fan-in. __syncthreads() drains
// vmcnt(0) before the flag store, so all of the block's sc1 data stores are
// LLC-visible before its flag flips. Monotonic counters (memset per replay).
// ---------------------------------------------------------------------------
#define NBLK 256
__device__ __forceinline__ void flag_barrier(unsigned int* flags, unsigned int target)
{
    __syncthreads();                    // all lanes' coherent stores are done
    if (threadIdx.x == 0)
        __hip_atomic_store(&flags[blockIdx.x * 4], target,
                           __ATOMIC_RELAXED, __HIP_MEMORY_SCOPE_AGENT);
    if (threadIdx.x < NBLK) {
        while (__hip_atomic_load(&flags[threadIdx.x * 4], __ATOMIC_RELAXED,
                                 __HIP_MEMORY_SCOPE_AGENT) < target)
            __builtin_amdgcn_s_sleep(1);
    }
    __syncthreads();
}

// ---------------------------------------------------------------------------
// All-CU sequential decoder (R2 structure + flag barrier). 256 blocks x 512
// threads; block owns 3 hidden dims (12 weight rows in LDS, loaded once).
// Per step 3 phases split by store-flag grid barriers. Cross-block state
// (Ha/Hb/Sc) accessed ONLY via sc1 LLC ops; read-only streams stay in L2.
// ---------------------------------------------------------------------------
__global__ __launch_bounds__(512)
void seq_coop(const float* __restrict__ gi,     // [B*T][2304]
              const float* __restrict__ G,      // [B*S][768]
              const float* __restrict__ Ft,     // [768][B*S]
              const float* __restrict__ gbias,  // [B*S]
              const float* __restrict__ h0,     // [B][768]
              const float* __restrict__ Whh,    // [2304][768] (raw input)
              const float* __restrict__ Wctx,   // [768][1536] (raw input)
              const float* __restrict__ bhh,    // [2304]
              const float* __restrict__ bctx,   // [768]
              float* __restrict__ Ha,           // [32][768]  h_new (post-attn)
              float* __restrict__ Hb,           // [32][768]  h_t (post-GRU)
              float* __restrict__ Sc,           // [32][128]  raw scores
              unsigned int* __restrict__ flags,
              bf16* __restrict__ Hseq)          // [B*T][768]
{
    const int bid  = blockIdx.x;
    const int tid  = threadIdx.x;
    const int w    = tid >> 6;          // 8 waves
    const int lane = tid & 63;
    const int kg   = lane & 7;          // k sub-chunk within wave
    const int bo   = lane >> 3;         // batch offset: b = bo + 8q
    const int j0   = bid * 3;

    __shared__ __align__(16) float Wlds[12][768];  // rr = gate*3+jj (r,z,n), 9+jj (c2)
    __shared__ float part[8][9][32];               // per-wave k-slice partials
    __shared__ float redsum[9][32];
    __shared__ float c2s[3][32];
    __shared__ float pT[128][33];                  // softmax probs, s-major (+pad)
    __shared__ float ctxp[3][4][32];

    // ---- load the block's 12 weight rows into LDS (once) ----
    for (int idx = tid; idx < 12 * 768; idx += 512) {
        int rr = idx / 768, k = idx - rr * 768;
        float v;
        if (rr < 9) {
            int gate = rr / 3, jj = rr - gate * 3;
            v = Whh[(size_t)(gate * 768 + j0 + jj) * 768 + k];
        } else {
            int jj = rr - 9;
            v = Wctx[(size_t)(j0 + jj) * 1536 + 768 + k];
        }
        (&Wlds[0][0])[idx] = v;
    }

    // hoisted pointwise constants (threads 0..95: jj = tid>>5, b = tid&31)
    float bhr = 0.f, bhz = 0.f, bhn = 0.f, bcv = 0.f;
    if (tid < 96) {
        int jj = tid >> 5;
        bhr = bhh[j0 + jj]; bhz = bhh[768 + j0 + jj]; bhn = bhh[1536 + j0 + jj];
        bcv = bctx[j0 + jj];
    }
    const int bstar = bid >> 3;           // scores: this block's batch
    const int s0    = (bid & 7) * 16;     // and 16-wide s slice
    const int k4b   = 3 * (8 * w + kg);   // this lane's float4 k-chunk

    unsigned int target = 1;
    __syncthreads();

#pragma unroll 1
    for (int t = 0; t < TT; ++t) {
        const float* hp = (t == 0) ? h0 : Ha;

        // early pointwise-input loads (latency hidden under the k-loop)
        float e_ir = 0.f, e_iz = 0.f, e_inn = 0.f, e_hprev = 0.f;
        if (tid < 96) {
            int jj = tid >> 5, bb = tid & 31;
            const float* gir = gi + (size_t)(bb * TT + t) * 2304 + j0 + jj;
            e_ir = gir[0]; e_iz = gir[768]; e_inn = gir[1536];
            e_hprev = ld1cg(hp + bb * 768 + j0 + jj);
        }

        // ---- Phase A: rows 0..8 (r,z,n) vs h_prev (coherent h reads) ----
        {
            float acc[9][4];
#pragma unroll
            for (int r = 0; r < 9; ++r)
#pragma unroll
                for (int q = 0; q < 4; ++q) acc[r][q] = 0.f;
            const float* hp_b = hp + bo * 768 + 4 * k4b;
            float2 h2[4][6];
#pragma unroll
            for (int q = 0; q < 4; ++q) {
                const float* hq = hp_b + q * 8 * 768;
#pragma unroll
                for (int i = 0; i < 6; ++i) h2[q][i] = ld2cg(hq + 2 * i);
            }
#pragma unroll
            for (int r = 0; r < 9; ++r) {
                const float* wr_ = &Wlds[r][4 * k4b];
#pragma unroll
                for (int i = 0; i < 6; ++i) {
                    float2 w2 = *(const float2*)(wr_ + 2 * i);
#pragma unroll
                    for (int q = 0; q < 4; ++q)
                        acc[r][q] += w2.x * h2[q][i].x + w2.y * h2[q][i].y;
                }
            }
#pragma unroll
            for (int r = 0; r < 9; ++r)
#pragma unroll
                for (int q = 0; q < 4; ++q) {
                    float v = acc[r][q];
                    v += __shfl_xor(v, 1); v += __shfl_xor(v, 2); v += __shfl_xor(v, 4);
                    if (kg == 0) part[w][r][bo + 8 * q] = v;
                }
        }
        __syncthreads();
        if (tid < 288) {
            int rr = tid >> 5, bb = tid & 31;
            float s = 0.f;
#pragma unroll
            for (int ww = 0; ww < 8; ++ww) s += part[ww][rr][bb];
            redsum[rr][bb] = s;
        }
        __syncthreads();
        if (tid < 96) {
            int jj = tid >> 5, bb = tid & 31;
            float r = sigmoidf_(e_ir + redsum[jj][bb] + bhr);
            float z = sigmoidf_(e_iz + redsum[3 + jj][bb] + bhz);
            float n = tanhf_(e_inn + r * (redsum[6 + jj][bb] + bhn));
            float ht = (1.f - z) * n + z * e_hprev;
            st1cg(&Hb[bb * 768 + j0 + jj], ht);
            Hseq[(size_t)(bb * TT + t) * 768 + j0 + jj] = (bf16)ht;
        }
        flag_barrier(flags, target); ++target;

        // ---- Phase B: c2 rows (9..11) vs ht, plus this block's 16 scores ----
        {
            float a2[3][4];
#pragma unroll
            for (int c = 0; c < 3; ++c)
#pragma unroll
                for (int q = 0; q < 4; ++q) a2[c][q] = 0.f;
            const float* hb_b = Hb + bo * 768 + 4 * k4b;
            float2 h2[4][6];
#pragma unroll
            for (int q = 0; q < 4; ++q) {
                const float* hq = hb_b + q * 8 * 768;
#pragma unroll
                for (int i = 0; i < 6; ++i) h2[q][i] = ld2cg(hq + 2 * i);
            }
#pragma unroll
            for (int c = 0; c < 3; ++c) {
                const float* wr_ = &Wlds[9 + c][4 * k4b];
#pragma unroll
                for (int i = 0; i < 6; ++i) {
                    float2 w2 = *(const float2*)(wr_ + 2 * i);
#pragma unroll
                    for (int q = 0; q < 4; ++q)
                        a2[c][q] += w2.x * h2[q][i].x + w2.y * h2[q][i].y;
                }
            }
#pragma unroll
            for (int c = 0; c < 3; ++c)
#pragma unroll
                for (int q = 0; q < 4; ++q) {
                    float v = a2[c][q];
                    v += __shfl_xor(v, 1); v += __shfl_xor(v, 2); v += __shfl_xor(v, 4);
                    if (kg == 0) part[w][c][bo + 8 * q] = v;
                }
        }
        {   // scores: wave w -> s = s0+2w, s0+2w+1; lanes split k (coalesced)
            const float* hb = Hb + bstar * 768;
            float2 a[6];
#pragma unroll
            for (int q = 0; q < 3; ++q) {
                a[2 * q]     = ld2cg(hb + 4 * (q * 64 + lane));
                a[2 * q + 1] = ld2cg(hb + 4 * (q * 64 + lane) + 2);
            }
#pragma unroll
            for (int ss = 0; ss < 2; ++ss) {
                const int s = s0 + 2 * w + ss;
                const float* grow = G + (size_t)(bstar * 128 + s) * 768;
                float sa = 0.f;
#pragma unroll
                for (int q = 0; q < 3; ++q) {
                    float4 g4 = *(const float4*)(grow + 4 * (q * 64 + lane));
                    sa += a[2 * q].x * g4.x + a[2 * q].y * g4.y
                        + a[2 * q + 1].x * g4.z + a[2 * q + 1].y * g4.w;
                }
#pragma unroll
                for (int d = 32; d > 0; d >>= 1) sa += __shfl_xor(sa, d);
                if (lane == 0)
                    st1cg(&Sc[bstar * 128 + s], sa + gbias[bstar * 128 + s]);
            }
        }
        flag_barrier(flags, target); ++target;

        // ---- Phase C: c2 reduce, softmax (redundant per block), ctx, h_new ----
        if (tid < 96) {
            int jj = tid >> 5, bb = tid & 31;
            float s = 0.f;
#pragma unroll
            for (int ww = 0; ww < 8; ++ww) s += part[ww][jj][bb];
            c2s[jj][bb] = s;
        }
        {   // softmax: wave w -> batches 4w..4w+3 (coherent Sc reads)
#pragma unroll
            for (int q = 0; q < 4; ++q) {
                int bb = 4 * w + q;
                float v0 = ld1cg(&Sc[bb * 128 + lane]);
                float v1 = ld1cg(&Sc[bb * 128 + 64 + lane]);
                float m = fmaxf(v0, v1);
#pragma unroll
                for (int d = 32; d > 0; d >>= 1) m = fmaxf(m, __shfl_xor(m, d));
                float e0 = expf(v0 - m), e1 = expf(v1 - m);
                float sum = e0 + e1;
#pragma unroll
                for (int d = 32; d > 0; d >>= 1) sum += __shfl_xor(sum, d);
                float inv = 1.f / sum;
                pT[lane][bb] = e0 * inv;
                pT[64 + lane][bb] = e1 * inv;
            }
        }
        __syncthreads();
        if (tid < 384) {   // ctx partials: (jj, sh, b), 32 s each, Ft contiguous
            int jj = tid >> 7, rem = tid & 127, sh = rem >> 5, bb = rem & 31;
            const float* fr = Ft + (size_t)(j0 + jj) * 4096 + bb * 128 + 32 * sh;
            float ca = 0.f;
#pragma unroll
            for (int q = 0; q < 8; ++q) {
                float4 f4 = *(const float4*)(fr + 4 * q);
                int sb = 32 * sh + 4 * q;
                ca += f4.x * pT[sb][bb] + f4.y * pT[sb + 1][bb]
                    + f4.z * pT[sb + 2][bb] + f4.w * pT[sb + 3][bb];
            }
            ctxp[jj][sh][bb] = ca;
        }
        __syncthreads();
        if (tid < 96) {
            int jj = tid >> 5, bb = tid & 31;
            float ctx = ctxp[jj][0][bb] + ctxp[jj][1][bb]
                      + ctxp[jj][2][bb] + ctxp[jj][3][bb];
            float u = c2s[jj][bb] + ctx + bcv;
            st1cg(&Ha[bb * 768 + j0 + jj], tanhf_(u));
        }
        flag_barrier(flags, target); ++target;
    }
}

// ---------------------------------------------------------------------------
// workspace layout (bytes), peak ~71.01MB:
//   0         gi      14155776   (dead after seq -> Wpredb alias)
//   14155776  G       12582912
//   26738688  F       12582912
//   39321600  xh       2359296
//   41680896  xl       2359296
//   44040192  wihh     3538944
//   47579136  wihl     3538944
//   51118080  eh       6291456   -- Ft [768][4096] aliases eh+el after gemms
//   57409536  el       6291456
//   63700992  wath     1179648
//   64880640  watl     1179648
//   66060288  wc1h     1179648
//   67239936  wc1l     1179648
//   68419584  Hseq     2359296   (bf16)
//   70778880  gbias      16384
//   70795264  Ha         98304
//   70893568  Hb         98304
//   70991872  Sc         16384
//   71008256  flags       4096   (256 x 16B-spread flag words)
// ---------------------------------------------------------------------------
extern "C" void kernel_launch(void* const* d_in, const int* in_sizes, int n_in,
                              void* d_out, int out_size, void* d_ws, size_t ws_size,
                              hipStream_t stream)
{
    const float* x      = (const float*)d_in[0];
    const float* h0     = (const float*)d_in[1];
    const float* E      = (const float*)d_in[2];
    const float* W_ih   = (const float*)d_in[3];
    const float* W_hh   = (const float*)d_in[4];
    const float* b_ih   = (const float*)d_in[5];
    const float* b_hh   = (const float*)d_in[6];
    const float* W_pred = (const float*)d_in[7];
    const float* b_pred = (const float*)d_in[8];
    const float* W_att  = (const float*)d_in[9];
    const float* b_att  = (const float*)d_in[10];
    const float* W_ctx  = (const float*)d_in[11];
    const float* b_ctx  = (const float*)d_in[12];
    float* out = (float*)d_out;

    char* ws = (char*)d_ws;
    float* gi    = (float*)(ws);
    float* G     = (float*)(ws + 14155776);
    float* F     = (float*)(ws + 26738688);
    bf16*  xh    = (bf16*)(ws + 39321600);
    bf16*  xl    = (bf16*)(ws + 41680896);
    bf16*  wihh  = (bf16*)(ws + 44040192);
    bf16*  wihl  = (bf16*)(ws + 47579136);
    bf16*  eh    = (bf16*)(ws + 51118080);
    bf16*  el    = (bf16*)(ws + 57409536);
    bf16*  wath  = (bf16*)(ws + 63700992);
    bf16*  watl  = (bf16*)(ws + 64880640);
    bf16*  wc1h  = (bf16*)(ws + 66060288);
    bf16*  wc1l  = (bf16*)(ws + 67239936);
    bf16*  Hseq  = (bf16*)(ws + 68419584);
    float* gbias = (float*)(ws + 70778880);
    float* Ha    = (float*)(ws + 70795264);
    float* Hb    = (float*)(ws + 70893568);
    float* Sc    = (float*)(ws + 70991872);
    unsigned int* flags = (unsigned int*)(ws + 71008256);
    float* Ft    = (float*)(ws + 51118080);   // aliases eh/el (dead by then)
    bf16*  Wpredb = (bf16*)(ws);              // aliases dead gi/G/F/xh/xl

    hipMemsetAsync(flags, 0, NBLK * 16, stream);  // flags fresh each replay

    // 1. splits / b_att fold
    split_ops<<<8832, 256, 0, stream>>>(x, W_ih, E, W_ctx, W_att,
                                        xh, xl, wihh, wihl, eh, el,
                                        wc1h, wc1l, wath, watl);
    gbias_k<<<1024, 256, 0, stream>>>(E, b_att, gbias);

    // 2. near-f32 precompute GEMMs (split-bf16, f32 out)
    gemm_split<<<dim3(18, 12), 256, 0, stream>>>(
        xh, xl, 768, wihh, wihl, 768, b_ih, gi, 2304, BB * TT, 2304, 768);
    gemm_split<<<dim3(6, 32), 256, 0, stream>>>(
        eh, el, 768, wath, watl, 768, nullptr, G, 768, BB * SS, 768, 768);
    gemm_split<<<dim3(6, 32), 256, 0, stream>>>(
        eh, el, 768, wc1h, wc1l, 768, nullptr, F, 768, BB * SS, 768, 768);
    transpose_f<<<dim3(128, 24), 256, 0, stream>>>(F, Ft);

    // 3. all-CU sequential recurrence (f32 path, 3 store-flag barriers/step)
    seq_coop<<<NBLK, 512, 0, stream>>>(gi, G, Ft, gbias, h0, W_hh, W_ctx,
                                       b_hh, b_ctx, Ha, Hb, Sc, flags, Hseq);

    // 4. W_pred -> bf16 (into now-dead region), then logits GEMM (f32 out)
    conv_pred<<<21747, 256, 0, stream>>>(W_pred, Wpredb);
    gemm_bt<<<dim3(227, 12), 256, 0, stream>>>(
        Hseq, 768, Wpredb, 768, b_pred, out, VV, BB * TT, VV, 768);
}